// Round 3
// baseline (76.198 us; speedup 1.0000x reference)
//
#include <hip/hip_runtime.h>

// out[p][i][s][l] = log( sum_j sum_k exp(e1[p][(i+j)%2][s][k]) * exp(e2[p][j][k][l]) )
// Hadamard-diagonalize the Z2 convolution:
//   U = (A0+A1)(B0+B1) = S0+S1 ; V = (A0-A1)(B0-B1) = S0-S1
//   out0 = log((U+V)/2), out1 = log((U-V)/2)
// where Ai = exp(e1[i]) (64x64 over [s][k]), Bj = exp(e2[j]) (64x64 over [k][l]).
// N(0,1) inputs -> exp <= ~250, sums <= ~1e7: no overflow, no max-subtraction needed.
//
// Grid: 2 blocks per (b1,b2) pair (512 total), each owning a 32-row half of s.
// 48 KiB LDS/block -> 2 blocks/CU resident: one block's matmul overlaps the
// other's global staging (1 block/CU would serialize the phases).

__global__ __launch_bounds__(256) void trellis_lse_kernel(
    const float* __restrict__ e1,
    const float* __restrict__ e2,
    float* __restrict__ out)
{
    __shared__ float As[2048];  // (A0+A1) rows [32h, 32h+32), natural [s][k]
    __shared__ float Ad[2048];  // (A0-A1) same rows
    __shared__ float Bs[4096];  // B0+B1, natural [k][l]
    __shared__ float Bd[4096];  // B0-B1

    const int tid  = threadIdx.x;
    const int pair = blockIdx.x >> 1;
    const int h    = blockIdx.x & 1;          // which 32-row half of s
    const size_t base = (size_t)pair * 8192;

    const float4* __restrict__ e1v = (const float4*)(e1 + base);
    const float4* __restrict__ e2v = (const float4*)(e2 + base);
    float4* Asv = (float4*)As;
    float4* Adv = (float4*)Ad;
    float4* Bsv = (float4*)Bs;
    float4* Bdv = (float4*)Bd;

    // ---- stage: exp + Hadamard (sum/diff) into LDS, fully coalesced ----
    const int h512 = h << 9;                  // float4 offset of our A-row half
    #pragma unroll
    for (int rr = 0; rr < 2; ++rr) {          // A half: 512 float4 per matrix
        const int f = rr * 256 + tid;
        float4 a0 = e1v[h512 + f];
        float4 a1 = e1v[1024 + h512 + f];
        float4 s4, d4;
        float ea, eb;
        ea = __expf(a0.x); eb = __expf(a1.x); s4.x = ea + eb; d4.x = ea - eb;
        ea = __expf(a0.y); eb = __expf(a1.y); s4.y = ea + eb; d4.y = ea - eb;
        ea = __expf(a0.z); eb = __expf(a1.z); s4.z = ea + eb; d4.z = ea - eb;
        ea = __expf(a0.w); eb = __expf(a1.w); s4.w = ea + eb; d4.w = ea - eb;
        Asv[f] = s4; Adv[f] = d4;
    }
    #pragma unroll
    for (int rr = 0; rr < 4; ++rr) {          // B full: 1024 float4 per matrix
        const int f = rr * 256 + tid;
        float4 b0 = e2v[f];
        float4 b1 = e2v[1024 + f];
        float4 s4, d4;
        float ea, eb;
        ea = __expf(b0.x); eb = __expf(b1.x); s4.x = ea + eb; d4.x = ea - eb;
        ea = __expf(b0.y); eb = __expf(b1.y); s4.y = ea + eb; d4.y = ea - eb;
        ea = __expf(b0.z); eb = __expf(b1.z); s4.z = ea + eb; d4.z = ea - eb;
        ea = __expf(b0.w); eb = __expf(b1.w); s4.w = ea + eb; d4.w = ea - eb;
        Bsv[f] = s4; Bdv[f] = d4;
    }
    __syncthreads();

    // ---- two 32x64x64 fp32 matmuls: U = As*Bs, V = Ad*Bd ----
    // 4 waves; wave w -> local rows [8w, 8w+8); lane -> output column l
    const int w    = tid >> 6;
    const int lane = tid & 63;
    const int row0 = w << 3;

    float accU[8], accV[8];
    #pragma unroll
    for (int r = 0; r < 8; ++r) { accU[r] = 0.0f; accV[r] = 0.0f; }

    #pragma unroll 4
    for (int k4 = 0; k4 < 16; ++k4) {
        const int k = k4 << 2;
        // B column fragments: stride-1 across lanes (2-way aliasing = free)
        const float bs0 = Bs[(k + 0) * 64 + lane];
        const float bs1 = Bs[(k + 1) * 64 + lane];
        const float bs2 = Bs[(k + 2) * 64 + lane];
        const float bs3 = Bs[(k + 3) * 64 + lane];
        const float bd0 = Bd[(k + 0) * 64 + lane];
        const float bd1 = Bd[(k + 1) * 64 + lane];
        const float bd2 = Bd[(k + 2) * 64 + lane];
        const float bd3 = Bd[(k + 3) * 64 + lane];
        #pragma unroll
        for (int r = 0; r < 8; ++r) {
            // lane-uniform addresses -> LDS broadcast (free)
            const float4 ap = *(const float4*)&As[(row0 + r) * 64 + k];
            const float4 ad = *(const float4*)&Ad[(row0 + r) * 64 + k];
            accU[r] = fmaf(ap.x, bs0, accU[r]);
            accU[r] = fmaf(ap.y, bs1, accU[r]);
            accU[r] = fmaf(ap.z, bs2, accU[r]);
            accU[r] = fmaf(ap.w, bs3, accU[r]);
            accV[r] = fmaf(ad.x, bd0, accV[r]);
            accV[r] = fmaf(ad.y, bd1, accV[r]);
            accV[r] = fmaf(ad.z, bd2, accV[r]);
            accV[r] = fmaf(ad.w, bd3, accV[r]);
        }
    }

    // ---- epilogue: combine Hadamard halves, log, coalesced stores ----
    // global s-row = 32h + row0 + r ; i stride = 4096
    float* __restrict__ o0 = out + base + (size_t)((h << 5) + row0) * 64 + lane;
    float* __restrict__ o1 = o0 + 4096;
    #pragma unroll
    for (int r = 0; r < 8; ++r) {
        const float u = accU[r];
        const float v = accV[r];
        o0[r * 64] = __logf(0.5f * (u + v));
        o1[r * 64] = __logf(0.5f * (u - v));
    }
}

extern "C" void kernel_launch(void* const* d_in, const int* in_sizes, int n_in,
                              void* d_out, int out_size, void* d_ws, size_t ws_size,
                              hipStream_t stream)
{
    const float* e1 = (const float*)d_in[0];
    const float* e2 = (const float*)d_in[1];
    float* out = (float*)d_out;
    // 256 (b1,b2) pairs, two blocks each (row-halves of s)
    hipLaunchKernelGGL(trellis_lse_kernel, dim3(512), dim3(256), 0, stream,
                       e1, e2, out);
}

// Round 7
// 69.391 us; speedup vs baseline: 1.0981x; 1.0981x over previous
//
#include <hip/hip_runtime.h>

// out[p][i][s][l] = log( sum_j sum_k exp(e1[p][(i+j)%2][s][k]) * exp(e2[p][j][k][l]) )
// Direct form (all-positive sums, bf16-safe; avoids Hadamard cancellation):
//   S0 = A0*B0 + A1*B1 ; S1 = A1*B0 + A0*B1 ; out_i = log(S_i)
// with Ai = exp(e1[i]) (64x64 [s][k]), Bj = exp(e2[j]) (64x64 [k][l]) per pair.
// Matmuls in bf16 MFMA (16x16x32, fp32 accum). exp<=~250 -> bf16-safe range.
//
// Grid: 2 blocks per pair (512), each owning a 32-row half of s. ~26 KB LDS
// -> 2 blocks/CU resident. Pair decode: pair = bid&255, h = bid>>8, so both
// halves of a pair land on the SAME XCD (bid%8 == (bid+256)%8) and the
// duplicated e2 read hits that XCD's L2.

typedef short short4v __attribute__((ext_vector_type(4)));
typedef short short8v __attribute__((ext_vector_type(8)));
typedef float float4v __attribute__((ext_vector_type(4)));

#define LDA 72   // A row pitch (bf16): 144 B -> ds_read_b128 frags, 16B-aligned, ~2-way banks
#define LDB 68   // B row pitch (bf16): 136 B -> ds_read_u16 frags 2-way (free), 8B-aligned writes

// exp then round-to-nearest-even bf16, as raw bits
__device__ __forceinline__ short expbf(float x) {
    float f = __expf(x);
    unsigned u = __builtin_bit_cast(unsigned, f);
    u += 0x7fffu + ((u >> 16) & 1u);
    return (short)(u >> 16);
}

__global__ __launch_bounds__(256) void trellis_mfma_kernel(
    const float* __restrict__ e1,
    const float* __restrict__ e2,
    float* __restrict__ out)
{
    __shared__ __align__(16) short A0s[32 * LDA];
    __shared__ __align__(16) short A1s[32 * LDA];
    __shared__ __align__(16) short B0s[64 * LDB];
    __shared__ __align__(16) short B1s[64 * LDB];

    const int tid  = threadIdx.x;
    const int pair = blockIdx.x & 255;        // same-XCD pairing: b and b+256
    const int h    = blockIdx.x >> 8;         // which 32-row half of s
    const size_t base = (size_t)pair * 8192;

    const float4* __restrict__ e1v = (const float4*)(e1 + base);
    const float4* __restrict__ e2v = (const float4*)(e2 + base);

    // ---- stage: exp -> bf16 into LDS, coalesced float4 global reads ----
    #pragma unroll
    for (int it = 0; it < 2; ++it) {          // A half: 512 float4 per matrix
        const int f = it * 256 + tid;         // f = r*16 + c4, r in [0,32)
        const int r = f >> 4, c4 = f & 15;
        const float4 a0 = e1v[h * 512 + f];
        const float4 a1 = e1v[1024 + h * 512 + f];
        short4v p0, p1;
        p0.x = expbf(a0.x); p0.y = expbf(a0.y); p0.z = expbf(a0.z); p0.w = expbf(a0.w);
        p1.x = expbf(a1.x); p1.y = expbf(a1.y); p1.z = expbf(a1.z); p1.w = expbf(a1.w);
        *(short4v*)&A0s[r * LDA + c4 * 4] = p0;
        *(short4v*)&A1s[r * LDA + c4 * 4] = p1;
    }
    #pragma unroll
    for (int it = 0; it < 4; ++it) {          // B full: 1024 float4 per matrix
        const int f = it * 256 + tid;         // f = k*16 + c4
        const int k = f >> 4, c4 = f & 15;
        const float4 b0 = e2v[f];
        const float4 b1 = e2v[1024 + f];
        short4v p0, p1;
        p0.x = expbf(b0.x); p0.y = expbf(b0.y); p0.z = expbf(b0.z); p0.w = expbf(b0.w);
        p1.x = expbf(b1.x); p1.y = expbf(b1.y); p1.z = expbf(b1.z); p1.w = expbf(b1.w);
        *(short4v*)&B0s[k * LDB + c4 * 4] = p0;
        *(short4v*)&B1s[k * LDB + c4 * 4] = p1;
    }
    __syncthreads();

    // ---- MFMA: wave w -> rows r0..r0+15 (local), cols c0..c0+31 (two 16-tiles) ----
    const int w    = tid >> 6;
    const int lane = tid & 63;
    const int ln   = lane & 15;
    const int g    = lane >> 4;
    const int r0   = (w >> 1) * 16;
    const int c0   = (w & 1) * 32;

    // A fragments: elem i = A[r0+ln][ks*32 + g*8 + i]  (single b128 each)
    short8v a0f[2], a1f[2];
    #pragma unroll
    for (int ks = 0; ks < 2; ++ks) {
        const int off = (r0 + ln) * LDA + ks * 32 + g * 8;
        a0f[ks] = *(const short8v*)&A0s[off];
        a1f[ks] = *(const short8v*)&A1s[off];
    }

    // B fragments: elem i = B[ks*32 + g*8 + i][c0 + ct*16 + ln]
    // (same slot->k bijection as A => contraction correct independent of HW k order)
    short8v b0f[2][2], b1f[2][2];   // [ct][ks]
    #pragma unroll
    for (int ct = 0; ct < 2; ++ct) {
        #pragma unroll
        for (int ks = 0; ks < 2; ++ks) {
            const int col = c0 + ct * 16 + ln;
            const int kb  = ks * 32 + g * 8;
            short8v t0, t1;
            #pragma unroll
            for (int i = 0; i < 8; ++i) {
                t0[i] = B0s[(kb + i) * LDB + col];
                t1[i] = B1s[(kb + i) * LDB + col];
            }
            b0f[ct][ks] = t0;
            b1f[ct][ks] = t1;
        }
    }

    float4v acc0[2] = {{0.f,0.f,0.f,0.f}, {0.f,0.f,0.f,0.f}};  // S0 = A0B0 + A1B1
    float4v acc1[2] = {{0.f,0.f,0.f,0.f}, {0.f,0.f,0.f,0.f}};  // S1 = A1B0 + A0B1
    #pragma unroll
    for (int ct = 0; ct < 2; ++ct) {
        #pragma unroll
        for (int ks = 0; ks < 2; ++ks) {
            acc0[ct] = __builtin_amdgcn_mfma_f32_16x16x32_bf16(a0f[ks], b0f[ct][ks], acc0[ct], 0, 0, 0);
            acc0[ct] = __builtin_amdgcn_mfma_f32_16x16x32_bf16(a1f[ks], b1f[ct][ks], acc0[ct], 0, 0, 0);
            acc1[ct] = __builtin_amdgcn_mfma_f32_16x16x32_bf16(a1f[ks], b0f[ct][ks], acc1[ct], 0, 0, 0);
            acc1[ct] = __builtin_amdgcn_mfma_f32_16x16x32_bf16(a0f[ks], b1f[ct][ks], acc1[ct], 0, 0, 0);
        }
    }

    // ---- epilogue: log + store. D layout (m89-verified): col=ln, row=g*4+j ----
    const int srow0 = 32 * h + r0 + g * 4;
    #pragma unroll
    for (int ct = 0; ct < 2; ++ct) {
        const int col = c0 + ct * 16 + ln;
        #pragma unroll
        for (int j = 0; j < 4; ++j) {
            const size_t o = base + (size_t)(srow0 + j) * 64 + col;
            out[o]        = __logf(acc0[ct][j]);   // i = 0
            out[o + 4096] = __logf(acc1[ct][j]);   // i = 1
        }
    }
}

extern "C" void kernel_launch(void* const* d_in, const int* in_sizes, int n_in,
                              void* d_out, int out_size, void* d_ws, size_t ws_size,
                              hipStream_t stream)
{
    const float* e1 = (const float*)d_in[0];
    const float* e2 = (const float*)d_in[1];
    float* out = (float*)d_out;
    // 256 pairs x 2 row-half blocks; halves of a pair share an XCD (b, b+256)
    hipLaunchKernelGGL(trellis_mfma_kernel, dim3(512), dim3(256), 0, stream,
                       e1, e2, out);
}

// Round 8
// 69.258 us; speedup vs baseline: 1.1002x; 1.0019x over previous
//
#include <hip/hip_runtime.h>

// out[p][i][s][l] = log( sum_j sum_k exp(e1[p][(i+j)%2][s][k]) * exp(e2[p][j][k][l]) )
// Direct form (all-positive sums, bf16-safe; avoids Hadamard cancellation):
//   S0 = A0*B0 + A1*B1 ; S1 = A1*B0 + A0*B1 ; out_i = log(S_i)
// with Ai = exp(e1[i]) (64x64 [s][k]), Bj = exp(e2[j]) (64x64 [k][l]) per pair.
// Matmuls in bf16 MFMA (16x16x32, fp32 accum). exp<=~250 -> bf16-safe range.
//
// R8 change (one lever): 512 threads/block (8 waves) instead of 256 (4 waves).
// Per-thread serial chain halves; occupancy 8 -> 16 waves/CU. Grid/LDS/XCD
// pairing unchanged: 2 blocks per pair, pair = bid&255, h = bid>>8 keeps both
// halves of a pair on one XCD so the duplicated e2 read is an L2 hit.

typedef short short4v __attribute__((ext_vector_type(4)));
typedef short short8v __attribute__((ext_vector_type(8)));
typedef float float4v __attribute__((ext_vector_type(4)));

#define LDA 72   // A row pitch (bf16): 144 B -> ds_read_b128 frags, 16B-aligned
#define LDB 68   // B row pitch (bf16): 136 B -> ds_read_u16 frags ~2-way (free)

// exp then round-to-nearest-even bf16, as raw bits (measured-correct in R7)
__device__ __forceinline__ short expbf(float x) {
    float f = __expf(x);
    unsigned u = __builtin_bit_cast(unsigned, f);
    u += 0x7fffu + ((u >> 16) & 1u);
    return (short)(u >> 16);
}

__global__ __launch_bounds__(512) void trellis_mfma_kernel(
    const float* __restrict__ e1,
    const float* __restrict__ e2,
    float* __restrict__ out)
{
    __shared__ __align__(16) short A0s[32 * LDA];
    __shared__ __align__(16) short A1s[32 * LDA];
    __shared__ __align__(16) short B0s[64 * LDB];
    __shared__ __align__(16) short B1s[64 * LDB];

    const int tid  = threadIdx.x;
    const int pair = blockIdx.x & 255;        // same-XCD pairing: b and b+256
    const int h    = blockIdx.x >> 8;         // which 32-row half of s
    const size_t base = (size_t)pair * 8192;

    const float4* __restrict__ e1v = (const float4*)(e1 + base);
    const float4* __restrict__ e2v = (const float4*)(e2 + base);

    // ---- stage: exp -> bf16 into LDS, coalesced float4 global reads ----
    {   // A half: 512 float4 per matrix -> 1 per thread
        const int f = tid;                    // f = r*16 + c4, r in [0,32)
        const int r = f >> 4, c4 = f & 15;
        const float4 a0 = e1v[h * 512 + f];
        const float4 a1 = e1v[1024 + h * 512 + f];
        short4v p0, p1;
        p0.x = expbf(a0.x); p0.y = expbf(a0.y); p0.z = expbf(a0.z); p0.w = expbf(a0.w);
        p1.x = expbf(a1.x); p1.y = expbf(a1.y); p1.z = expbf(a1.z); p1.w = expbf(a1.w);
        *(short4v*)&A0s[r * LDA + c4 * 4] = p0;
        *(short4v*)&A1s[r * LDA + c4 * 4] = p1;
    }
    #pragma unroll
    for (int it = 0; it < 2; ++it) {          // B full: 1024 float4 per matrix -> 2 per thread
        const int f = it * 512 + tid;         // f = k*16 + c4
        const int k = f >> 4, c4 = f & 15;
        const float4 b0 = e2v[f];
        const float4 b1 = e2v[1024 + f];
        short4v p0, p1;
        p0.x = expbf(b0.x); p0.y = expbf(b0.y); p0.z = expbf(b0.z); p0.w = expbf(b0.w);
        p1.x = expbf(b1.x); p1.y = expbf(b1.y); p1.z = expbf(b1.z); p1.w = expbf(b1.w);
        *(short4v*)&B0s[k * LDB + c4 * 4] = p0;
        *(short4v*)&B1s[k * LDB + c4 * 4] = p1;
    }
    __syncthreads();

    // ---- MFMA: 8 waves; wave w -> local rows rt*16..+16, cols ct*16..+16 ----
    const int w    = tid >> 6;
    const int lane = tid & 63;
    const int ln   = lane & 15;
    const int g    = lane >> 4;
    const int r0   = (w >> 2) * 16;           // rt in {0,1}
    const int c0   = (w & 3) * 16;            // ct in {0..3}

    // A fragments: elem i = A[r0+ln][ks*32 + g*8 + i]  (single b128 each)
    short8v a0f[2], a1f[2];
    #pragma unroll
    for (int ks = 0; ks < 2; ++ks) {
        const int off = (r0 + ln) * LDA + ks * 32 + g * 8;
        a0f[ks] = *(const short8v*)&A0s[off];
        a1f[ks] = *(const short8v*)&A1s[off];
    }

    // B fragments: elem i = B[ks*32 + g*8 + i][c0 + ln]
    // (same slot->k bijection as A => contraction correct independent of HW k order)
    short8v b0f[2], b1f[2];
    #pragma unroll
    for (int ks = 0; ks < 2; ++ks) {
        const int kb = ks * 32 + g * 8;
        short8v t0, t1;
        #pragma unroll
        for (int i = 0; i < 8; ++i) {
            t0[i] = B0s[(kb + i) * LDB + c0 + ln];
            t1[i] = B1s[(kb + i) * LDB + c0 + ln];
        }
        b0f[ks] = t0;
        b1f[ks] = t1;
    }

    float4v acc0 = {0.f, 0.f, 0.f, 0.f};      // S0 = A0B0 + A1B1
    float4v acc1 = {0.f, 0.f, 0.f, 0.f};      // S1 = A1B0 + A0B1
    #pragma unroll
    for (int ks = 0; ks < 2; ++ks) {
        acc0 = __builtin_amdgcn_mfma_f32_16x16x32_bf16(a0f[ks], b0f[ks], acc0, 0, 0, 0);
        acc0 = __builtin_amdgcn_mfma_f32_16x16x32_bf16(a1f[ks], b1f[ks], acc0, 0, 0, 0);
        acc1 = __builtin_amdgcn_mfma_f32_16x16x32_bf16(a1f[ks], b0f[ks], acc1, 0, 0, 0);
        acc1 = __builtin_amdgcn_mfma_f32_16x16x32_bf16(a0f[ks], b1f[ks], acc1, 0, 0, 0);
    }

    // ---- epilogue: log + store. D layout (m89-verified): col=ln, row=g*4+j ----
    const int srow0 = 32 * h + r0 + g * 4;
    const int col   = c0 + ln;
    #pragma unroll
    for (int j = 0; j < 4; ++j) {
        const size_t o = base + (size_t)(srow0 + j) * 64 + col;
        out[o]        = __logf(acc0[j]);      // i = 0
        out[o + 4096] = __logf(acc1[j]);      // i = 1
    }
}

extern "C" void kernel_launch(void* const* d_in, const int* in_sizes, int n_in,
                              void* d_out, int out_size, void* d_ws, size_t ws_size,
                              hipStream_t stream)
{
    const float* e1 = (const float*)d_in[0];
    const float* e2 = (const float*)d_in[1];
    float* out = (float*)d_out;
    // 256 pairs x 2 row-half blocks; halves of a pair share an XCD (b, b+256)
    hipLaunchKernelGGL(trellis_mfma_kernel, dim3(512), dim3(512), 0, stream,
                       e1, e2, out);
}